// Round 9
// baseline (615.667 us; speedup 1.0000x reference)
//
#include <hip/hip_runtime.h>
#include <hip/hip_fp16.h>

#define NNODES 50000
#define NEDGES 800000
#define ETOT   (NNODES + NEDGES)   // 850000 edges incl. self-loops
#define NH     8
#define HID    64
#define D1     512                  // NH*HID
#define INC    512
#define OUTC   128
#define NEG    0.2f
#define MPAD   50048                // 391*128, padded row count for GEMM tiles

typedef __attribute__((ext_vector_type(8))) short short8;
typedef __attribute__((ext_vector_type(4))) float f32x4;
typedef _Float16 half8v __attribute__((ext_vector_type(8)));
typedef _Float16 half2v __attribute__((ext_vector_type(2)));

__device__ __forceinline__ ushort f2h_bits(float x) {
    _Float16 h = (_Float16)x; return __builtin_bit_cast(ushort, h);
}
__device__ __forceinline__ float h2f(ushort b) {
    return (float)__builtin_bit_cast(_Float16, b);
}
__device__ __forceinline__ uint splat_h2(float p) {
    uint b = (uint)f2h_bits(p); return b | (b << 16);
}
__device__ __forceinline__ half2v as_h2(uint u) { return __builtin_bit_cast(half2v, u); }
__device__ __forceinline__ float leaky(float v) { return v >= 0.f ? v : NEG * v; }

// ---------------- CSR build ----------------
__global__ void count_deg(const int* __restrict__ ei, int* __restrict__ deg) {
    int i = blockIdx.x * 256 + threadIdx.x;
    if (i >= ETOT) return;
    int dst = (i < NEDGES) ? ei[NEDGES + i] : (i - NEDGES);
    atomicAdd(&deg[dst], 1);
}

__global__ void scan_deg(const int* __restrict__ deg, int* __restrict__ rs,
                         int* __restrict__ cur) {
    __shared__ int part[1024];
    const int n = NNODES;
    const int CH = (n + 1023) / 1024;
    int t = threadIdx.x;
    int lo = t * CH, hi = min(lo + CH, n);
    int s = 0;
    for (int i = lo; i < hi; ++i) s += deg[i];
    part[t] = s;
    __syncthreads();
    for (int off = 1; off < 1024; off <<= 1) {
        int v = (t >= off) ? part[t - off] : 0;
        __syncthreads();
        part[t] += v;
        __syncthreads();
    }
    int run = (t == 0) ? 0 : part[t - 1];
    for (int i = lo; i < hi; ++i) { rs[i] = run; cur[i] = run; run += deg[i]; }
    if (hi == n) rs[n] = run;
}

__global__ void scatter_edges(const int* __restrict__ ei, int* __restrict__ cursor,
                              int* __restrict__ csr_src) {
    int i = blockIdx.x * 256 + threadIdx.x;
    if (i >= ETOT) return;
    int src, dst;
    if (i < NEDGES) { src = ei[i]; dst = ei[NEDGES + i]; }
    else            { src = dst = i - NEDGES; }
    int pos = atomicAdd(&cursor[dst], 1);
    csr_src[pos] = src;
}

// ---------------- dtype prep (f16) ----------------
__global__ void cast_f16(const float* __restrict__ x, ushort* __restrict__ xh, int n4) {
    int i = blockIdx.x * 256 + threadIdx.x;
    if (i >= n4) return;
    float4 v = *(const float4*)&x[(size_t)i * 4];
    ushort4 o = { f2h_bits(v.x), f2h_bits(v.y), f2h_bits(v.z), f2h_bits(v.w) };
    *(ushort4*)&xh[(size_t)i * 4] = o;
}

// WT[n][k] = W[k][n], f16 out.
__global__ void cast_wT(const float* __restrict__ W, ushort* __restrict__ WT, int K, int N) {
    int idx = blockIdx.x * 256 + threadIdx.x;
    if (idx >= K * N) return;
    int n = idx / K, k = idx - n * K;
    WT[idx] = f2h_bits(W[(size_t)k * N + n]);
}

// ---------------- layer-1 GEMM (128x128, BK=64) + fused attention dots ----------------
template<int KDIM>
__global__ __launch_bounds__(256) void gemm1_f16(const ushort* __restrict__ A,
                                                 const ushort* __restrict__ Bt,
                                                 ushort* __restrict__ C,
                                                 const float* __restrict__ a_src,
                                                 const float* __restrict__ a_dst,
                                                 float* __restrict__ es,
                                                 float* __restrict__ ed,
                                                 int M, int N) {
    __shared__ __align__(16) ushort Asl[128 * 64];
    __shared__ __align__(16) ushort Bsl[128 * 64];
    const int tid  = threadIdx.x;
    const int lane = tid & 63;
    const int wid  = tid >> 6;
    const int wr   = wid >> 1, wc = wid & 1;
    const int fr   = lane & 15, fq = lane >> 4;
    const int m0   = blockIdx.x * 128;
    const int n0   = blockIdx.y * 128;

    f32x4 acc[4][4] = {};
    const int gcol = (((lane & 7) ^ ((lane >> 3) & 7))) * 8;

    for (int k0 = 0; k0 < KDIM; k0 += 64) {
        __syncthreads();
        #pragma unroll
        for (int i = 0; i < 4; ++i) {
            int chunk = wid * 4 + i;
            int r = chunk * 8 + (lane >> 3);
            const ushort* ga = A  + (size_t)(m0 + r) * KDIM + k0 + gcol;
            const ushort* gb = Bt + (size_t)(n0 + r) * KDIM + k0 + gcol;
            __builtin_amdgcn_global_load_lds(
                (const __attribute__((address_space(1))) void*)ga,
                (__attribute__((address_space(3))) void*)(Asl + chunk * 512), 16, 0, 0);
            __builtin_amdgcn_global_load_lds(
                (const __attribute__((address_space(1))) void*)gb,
                (__attribute__((address_space(3))) void*)(Bsl + chunk * 512), 16, 0, 0);
        }
        __syncthreads();
        #pragma unroll
        for (int ks = 0; ks < 2; ++ks) {
            short8 a[4], b[4];
            #pragma unroll
            for (int m = 0; m < 4; ++m) {
                int row = wr * 64 + m * 16 + fr;
                int slot = (ks * 4 + fq) ^ (fr & 7);
                a[m] = *(const short8*)&Asl[row * 64 + slot * 8];
            }
            #pragma unroll
            for (int n = 0; n < 4; ++n) {
                int row = wc * 64 + n * 16 + fr;
                int slot = (ks * 4 + fq) ^ (fr & 7);
                b[n] = *(const short8*)&Bsl[row * 64 + slot * 8];
            }
            #pragma unroll
            for (int m = 0; m < 4; ++m)
                #pragma unroll
                for (int n = 0; n < 4; ++n)
                    acc[m][n] = __builtin_amdgcn_mfma_f32_16x16x32_f16(
                        __builtin_bit_cast(half8v, a[m]),
                        __builtin_bit_cast(half8v, b[n]), acc[m][n], 0, 0, 0);
        }
    }
    // C store
    #pragma unroll
    for (int m = 0; m < 4; ++m) {
        #pragma unroll
        for (int r = 0; r < 4; ++r) {
            int row = m0 + wr * 64 + m * 16 + fq * 4 + r;
            if (row >= M) continue;
            #pragma unroll
            for (int n = 0; n < 4; ++n)
                C[(size_t)row * N + n0 + wc * 64 + n * 16 + fr] = f2h_bits(acc[m][n][r]);
        }
    }
    // fused dots: this wave owns head h = (n0 + wc*64)/64 for its 64 rows
    {
        int h = (n0 + wc * 64) >> 6;
        float as[4], ad[4];
        #pragma unroll
        for (int n = 0; n < 4; ++n) {
            as[n] = a_src[h * HID + n * 16 + fr];
            ad[n] = a_dst[h * HID + n * 16 + fr];
        }
        #pragma unroll
        for (int m = 0; m < 4; ++m) {
            #pragma unroll
            for (int r = 0; r < 4; ++r) {
                float s = 0.f, d = 0.f;
                #pragma unroll
                for (int n = 0; n < 4; ++n) {
                    float v = acc[m][n][r];
                    s += v * as[n];
                    d += v * ad[n];
                }
                #pragma unroll
                for (int off = 1; off < 16; off <<= 1) {
                    s += __shfl_xor(s, off);
                    d += __shfl_xor(d, off);
                }
                if (fr == 0) {
                    int row = m0 + wr * 64 + m * 16 + fq * 4 + r;
                    if (row < M) {
                        es[row * NH + h] = s;
                        ed[row * NH + h] = d;
                    }
                }
            }
        }
    }
}

// ---------------- layer-2 GEMM (BM=64, BN=128) + fused dots2 (atomic partials) ----------------
template<int KDIM>
__global__ __launch_bounds__(256) void gemm2_f16(const ushort* __restrict__ A,
                                                 const ushort* __restrict__ Bt,
                                                 ushort* __restrict__ C,
                                                 const float* __restrict__ a_src,
                                                 const float* __restrict__ a_dst,
                                                 float* __restrict__ es,
                                                 float* __restrict__ ed,
                                                 int M, int N) {
    __shared__ __align__(16) ushort Asl[64 * 64];    // 8 KB
    __shared__ __align__(16) ushort Bsl[128 * 64];   // 16 KB
    const int tid  = threadIdx.x;
    const int lane = tid & 63;
    const int wid  = tid >> 6;
    const int wr   = wid >> 1, wc = wid & 1;
    const int fr   = lane & 15, fq = lane >> 4;
    const int m0   = blockIdx.x * 64;
    const int n0   = blockIdx.y * 128;

    f32x4 acc[2][4] = {};
    const int gcol = (((lane & 7) ^ ((lane >> 3) & 7))) * 8;

    for (int k0 = 0; k0 < KDIM; k0 += 64) {
        __syncthreads();
        #pragma unroll
        for (int i = 0; i < 2; ++i) {
            int chunk = wid * 2 + i;
            int r = chunk * 8 + (lane >> 3);
            const ushort* ga = A + (size_t)(m0 + r) * KDIM + k0 + gcol;
            __builtin_amdgcn_global_load_lds(
                (const __attribute__((address_space(1))) void*)ga,
                (__attribute__((address_space(3))) void*)(Asl + chunk * 512), 16, 0, 0);
        }
        #pragma unroll
        for (int i = 0; i < 4; ++i) {
            int chunk = wid * 4 + i;
            int r = chunk * 8 + (lane >> 3);
            const ushort* gb = Bt + (size_t)(n0 + r) * KDIM + k0 + gcol;
            __builtin_amdgcn_global_load_lds(
                (const __attribute__((address_space(1))) void*)gb,
                (__attribute__((address_space(3))) void*)(Bsl + chunk * 512), 16, 0, 0);
        }
        __syncthreads();
        #pragma unroll
        for (int ks = 0; ks < 2; ++ks) {
            short8 a[2], b[4];
            #pragma unroll
            for (int m = 0; m < 2; ++m) {
                int row = wr * 32 + m * 16 + fr;
                int slot = (ks * 4 + fq) ^ (fr & 7);
                a[m] = *(const short8*)&Asl[row * 64 + slot * 8];
            }
            #pragma unroll
            for (int n = 0; n < 4; ++n) {
                int row = wc * 64 + n * 16 + fr;
                int slot = (ks * 4 + fq) ^ (fr & 7);
                b[n] = *(const short8*)&Bsl[row * 64 + slot * 8];
            }
            #pragma unroll
            for (int m = 0; m < 2; ++m)
                #pragma unroll
                for (int n = 0; n < 4; ++n)
                    acc[m][n] = __builtin_amdgcn_mfma_f32_16x16x32_f16(
                        __builtin_bit_cast(half8v, a[m]),
                        __builtin_bit_cast(half8v, b[n]), acc[m][n], 0, 0, 0);
        }
    }
    #pragma unroll
    for (int m = 0; m < 2; ++m) {
        #pragma unroll
        for (int r = 0; r < 4; ++r) {
            int row = m0 + wr * 32 + m * 16 + fq * 4 + r;
            if (row >= M) continue;
            #pragma unroll
            for (int n = 0; n < 4; ++n)
                C[(size_t)row * N + n0 + wc * 64 + n * 16 + fr] = f2h_bits(acc[m][n][r]);
        }
    }
    // fused dots2: partial over this wave's 64 cols, atomicAdd into es/ed
    {
        int cb = n0 + wc * 64;
        float as[4], ad[4];
        #pragma unroll
        for (int n = 0; n < 4; ++n) {
            as[n] = a_src[cb + n * 16 + fr];
            ad[n] = a_dst[cb + n * 16 + fr];
        }
        #pragma unroll
        for (int m = 0; m < 2; ++m) {
            #pragma unroll
            for (int r = 0; r < 4; ++r) {
                float s = 0.f, d = 0.f;
                #pragma unroll
                for (int n = 0; n < 4; ++n) {
                    float v = acc[m][n][r];
                    s += v * as[n];
                    d += v * ad[n];
                }
                #pragma unroll
                for (int off = 1; off < 16; off <<= 1) {
                    s += __shfl_xor(s, off);
                    d += __shfl_xor(d, off);
                }
                if (fr == 0) {
                    int row = m0 + wr * 32 + m * 16 + fq * 4 + r;
                    if (row < M) {
                        atomicAdd(&es[row], s);
                        atomicAdd(&ed[row], d);
                    }
                }
            }
        }
    }
}

// ---------------- layer-1 aggregation ----------------
// 1 wave per node, 4 nodes per 256-block, no block barriers.
// Single-pass softmax (no max-sub: |e| small, exp safe in f32); alpha normalized
// in LDS before gather (<=1, f16-safe). Gather: dwordx4 unroll-4.
#define CAP1 128
__global__ __launch_bounds__(256) void attn1(const ushort* __restrict__ h1,
                                             const float* __restrict__ esrc,
                                             const float* __restrict__ edst,
                                             const int* __restrict__ rs,
                                             const int* __restrict__ csr_src,
                                             const float* __restrict__ b1,
                                             ushort* __restrict__ out1) {
    int t = threadIdx.x, lane = t & 63, w = t >> 6;
    int n = blockIdx.x * 4 + w;
    int beg = rs[n], deg = rs[n + 1] - beg;
    int dcap = min(deg, CAP1);
    __shared__ uint  alpha_sh[4][CAP1][9];   // pad 9: conflict-free
    __shared__ int   ssrc_sh[4][CAP1];
    uint (*alpha)[9] = alpha_sh[w];
    int* ss = ssrc_sh[w];

    for (int e = lane; e < dcap; e += 64) ss[e] = csr_src[beg + e];

    float4 edA = *(const float4*)&edst[n * NH];
    float4 edB = *(const float4*)&edst[n * NH + 4];
    float sm0 = 0.f, sm1 = 0.f, sm2 = 0.f, sm3 = 0.f;
    float sm4 = 0.f, sm5 = 0.f, sm6 = 0.f, sm7 = 0.f;

    // single pass: p = exp(leaky(es+ed)), store p bits, accumulate sums
    for (int e = lane; e < deg; e += 64) {
        int s = (e < CAP1) ? ss[e] : csr_src[beg + e];
        float4 eA = *(const float4*)&esrc[(size_t)s * NH];
        float4 eB = *(const float4*)&esrc[(size_t)s * NH + 4];
        float p0 = __expf(leaky(eA.x + edA.x));
        float p1 = __expf(leaky(eA.y + edA.y));
        float p2 = __expf(leaky(eA.z + edA.z));
        float p3 = __expf(leaky(eA.w + edA.w));
        float p4 = __expf(leaky(eB.x + edB.x));
        float p5 = __expf(leaky(eB.y + edB.y));
        float p6 = __expf(leaky(eB.z + edB.z));
        float p7 = __expf(leaky(eB.w + edB.w));
        if (e < CAP1) {
            alpha[e][0] = __float_as_uint(p0); alpha[e][1] = __float_as_uint(p1);
            alpha[e][2] = __float_as_uint(p2); alpha[e][3] = __float_as_uint(p3);
            alpha[e][4] = __float_as_uint(p4); alpha[e][5] = __float_as_uint(p5);
            alpha[e][6] = __float_as_uint(p6); alpha[e][7] = __float_as_uint(p7);
        }
        sm0 += p0; sm1 += p1; sm2 += p2; sm3 += p3;
        sm4 += p4; sm5 += p5; sm6 += p6; sm7 += p7;
    }
    #pragma unroll
    for (int off = 1; off < 64; off <<= 1) {
        sm0 += __shfl_xor(sm0, off); sm1 += __shfl_xor(sm1, off);
        sm2 += __shfl_xor(sm2, off); sm3 += __shfl_xor(sm3, off);
        sm4 += __shfl_xor(sm4, off); sm5 += __shfl_xor(sm5, off);
        sm6 += __shfl_xor(sm6, off); sm7 += __shfl_xor(sm7, off);
    }
    float ri0 = 1.f / (sm0 + 1e-16f), ri1 = 1.f / (sm1 + 1e-16f);
    float ri2 = 1.f / (sm2 + 1e-16f), ri3 = 1.f / (sm3 + 1e-16f);
    float ri4 = 1.f / (sm4 + 1e-16f), ri5 = 1.f / (sm5 + 1e-16f);
    float ri6 = 1.f / (sm6 + 1e-16f), ri7 = 1.f / (sm7 + 1e-16f);

    // normalize alpha in LDS -> packed half2 (static head index per loop)
    #define NORM(H, RI) \
        for (int e = lane; e < dcap; e += 64) \
            alpha[e][H] = splat_h2(__uint_as_float(alpha[e][H]) * RI);
    NORM(0, ri0) NORM(1, ri1) NORM(2, ri2) NORM(3, ri3)
    NORM(4, ri4) NORM(5, ri5) NORM(6, ri6) NORM(7, ri7)
    #undef NORM

    // per-lane head scalars for overflow path
    int h = lane >> 3;
    float riv[8] = { ri0, ri1, ri2, ri3, ri4, ri5, ri6, ri7 };
    float edv[8] = { edA.x, edA.y, edA.z, edA.w, edB.x, edB.y, edB.z, edB.w };
    float rih = riv[0], edn = edv[0];
    #pragma unroll
    for (int hh = 1; hh < 8; ++hh)
        if (h == hh) { rih = riv[hh]; edn = edv[hh]; }

    // gather: lane owns channels c0..c0+7, unroll-4
    int c0 = lane * 8;
    half2v aA0 = {}, aA1 = {}, aA2 = {}, aA3 = {};
    half2v aB0 = {}, aB1 = {}, aB2 = {}, aB3 = {};
    int e = 0;
    for (; e + 4 <= dcap; e += 4) {
        int s0i = ss[e], s1i = ss[e + 1], s2i = ss[e + 2], s3i = ss[e + 3];
        uint4 u0 = *(const uint4*)&h1[(size_t)s0i * D1 + c0];
        uint4 u1 = *(const uint4*)&h1[(size_t)s1i * D1 + c0];
        uint4 u2 = *(const uint4*)&h1[(size_t)s2i * D1 + c0];
        uint4 u3 = *(const uint4*)&h1[(size_t)s3i * D1 + c0];
        half2v p0 = as_h2(alpha[e][h]);
        half2v p1 = as_h2(alpha[e + 1][h]);
        half2v p2 = as_h2(alpha[e + 2][h]);
        half2v p3 = as_h2(alpha[e + 3][h]);
        aA0 = as_h2(u0.x) * p0 + aA0; aA1 = as_h2(u0.y) * p0 + aA1;
        aA2 = as_h2(u0.z) * p0 + aA2; aA3 = as_h2(u0.w) * p0 + aA3;
        aB0 = as_h2(u1.x) * p1 + aB0; aB1 = as_h2(u1.y) * p1 + aB1;
        aB2 = as_h2(u1.z) * p1 + aB2; aB3 = as_h2(u1.w) * p1 + aB3;
        aA0 = as_h2(u2.x) * p2 + aA0; aA1 = as_h2(u2.y) * p2 + aA1;
        aA2 = as_h2(u2.z) * p2 + aA2; aA3 = as_h2(u2.w) * p2 + aA3;
        aB0 = as_h2(u3.x) * p3 + aB0; aB1 = as_h2(u3.y) * p3 + aB1;
        aB2 = as_h2(u3.z) * p3 + aB2; aB3 = as_h2(u3.w) * p3 + aB3;
    }
    for (; e < dcap; ++e) {
        int s = ss[e];
        uint4 u = *(const uint4*)&h1[(size_t)s * D1 + c0];
        half2v p = as_h2(alpha[e][h]);
        aA0 = as_h2(u.x) * p + aA0; aA1 = as_h2(u.y) * p + aA1;
        aA2 = as_h2(u.z) * p + aA2; aA3 = as_h2(u.w) * p + aA3;
    }
    for (; e < deg; ++e) {   // overflow (deg > CAP1)
        int s = csr_src[beg + e];
        float p = __expf(leaky(esrc[(size_t)s * NH + h] + edn)) * rih;
        half2v ph = as_h2(splat_h2(p));
        uint4 u = *(const uint4*)&h1[(size_t)s * D1 + c0];
        aA0 = as_h2(u.x) * ph + aA0; aA1 = as_h2(u.y) * ph + aA1;
        aA2 = as_h2(u.z) * ph + aA2; aA3 = as_h2(u.w) * ph + aA3;
    }
    float4 bb0 = *(const float4*)&b1[c0];
    float4 bb1 = *(const float4*)&b1[c0 + 4];
    float o0 = fmaxf(((float)aA0[0] + (float)aB0[0]) + bb0.x, 0.f);
    float o1 = fmaxf(((float)aA0[1] + (float)aB0[1]) + bb0.y, 0.f);
    float o2 = fmaxf(((float)aA1[0] + (float)aB1[0]) + bb0.z, 0.f);
    float o3 = fmaxf(((float)aA1[1] + (float)aB1[1]) + bb0.w, 0.f);
    float o4 = fmaxf(((float)aA2[0] + (float)aB2[0]) + bb1.x, 0.f);
    float o5 = fmaxf(((float)aA2[1] + (float)aB2[1]) + bb1.y, 0.f);
    float o6 = fmaxf(((float)aA3[0] + (float)aB3[0]) + bb1.z, 0.f);
    float o7 = fmaxf(((float)aA3[1] + (float)aB3[1]) + bb1.w, 0.f);
    uint4 pk;
    pk.x = (uint)f2h_bits(o0) | ((uint)f2h_bits(o1) << 16);
    pk.y = (uint)f2h_bits(o2) | ((uint)f2h_bits(o3) << 16);
    pk.z = (uint)f2h_bits(o4) | ((uint)f2h_bits(o5) << 16);
    pk.w = (uint)f2h_bits(o6) | ((uint)f2h_bits(o7) << 16);
    *(uint4*)&out1[(size_t)n * D1 + c0] = pk;
}

// ---------------- layer-2 aggregation ----------------
// 16 nodes per 256-block; 16 lanes per node; lane owns 8 channels (dwordx4).
// Single-pass softmax (no max-sub), alpha normalized in LDS.
#define CAP2 128
__global__ __launch_bounds__(256) void attn2(const ushort* __restrict__ h2,
                                             const float* __restrict__ esrc,
                                             const float* __restrict__ edst,
                                             const int* __restrict__ rs,
                                             const int* __restrict__ csr_src,
                                             const float* __restrict__ b2,
                                             float* __restrict__ out) {
    int t = threadIdx.x;
    int g = t >> 4, lane16 = t & 15;
    int n = blockIdx.x * 16 + g;
    int beg = rs[n], deg = rs[n + 1] - beg;
    int dcap = min(deg, CAP2);
    __shared__ uint al_sh[16][CAP2];
    __shared__ int  ss_sh[16][CAP2];
    uint* al = al_sh[g];
    int*  ss = ss_sh[g];

    for (int e = lane16; e < dcap; e += 16) ss[e] = csr_src[beg + e];

    float edn = edst[n];
    float ssum = 0.f;
    for (int e = lane16; e < deg; e += 16) {
        int s = (e < CAP2) ? ss[e] : csr_src[beg + e];
        float p = __expf(leaky(esrc[s] + edn));
        if (e < CAP2) al[e] = __float_as_uint(p);
        ssum += p;
    }
    #pragma unroll
    for (int off = 1; off < 16; off <<= 1) ssum += __shfl_xor(ssum, off);
    float ri = 1.f / (ssum + 1e-16f);

    for (int e = lane16; e < dcap; e += 16)
        al[e] = splat_h2(__uint_as_float(al[e]) * ri);

    int c0 = lane16 * 8;
    half2v aA0 = {}, aA1 = {}, aA2 = {}, aA3 = {};
    half2v aB0 = {}, aB1 = {}, aB2 = {}, aB3 = {};
    int e = 0;
    for (; e + 2 <= dcap; e += 2) {
        int s0i = ss[e], s1i = ss[e + 1];
        uint4 u0 = *(const uint4*)&h2[(size_t)s0i * OUTC + c0];
        uint4 u1 = *(const uint4*)&h2[(size_t)s1i * OUTC + c0];
        half2v p0 = as_h2(al[e]);
        half2v p1 = as_h2(al[e + 1]);
        aA0 = as_h2(u0.x) * p0 + aA0; aA1 = as_h2(u0.y) * p0 + aA1;
        aA2 = as_h2(u0.z) * p0 + aA2; aA3 = as_h2(u0.w) * p0 + aA3;
        aB0 = as_h2(u1.x) * p1 + aB0; aB1 = as_h2(u1.y) * p1 + aB1;
        aB2 = as_h2(u1.z) * p1 + aB2; aB3 = as_h2(u1.w) * p1 + aB3;
    }
    for (; e < dcap; ++e) {
        int s = ss[e];
        uint4 u = *(const uint4*)&h2[(size_t)s * OUTC + c0];
        half2v p = as_h2(al[e]);
        aA0 = as_h2(u.x) * p + aA0; aA1 = as_h2(u.y) * p + aA1;
        aA2 = as_h2(u.z) * p + aA2; aA3 = as_h2(u.w) * p + aA3;
    }
    for (; e < deg; ++e) {   // overflow
        int s = csr_src[beg + e];
        float p = __expf(leaky(esrc[s] + edn)) * ri;
        half2v ph = as_h2(splat_h2(p));
        uint4 u = *(const uint4*)&h2[(size_t)s * OUTC + c0];
        aA0 = as_h2(u.x) * ph + aA0; aA1 = as_h2(u.y) * ph + aA1;
        aA2 = as_h2(u.z) * ph + aA2; aA3 = as_h2(u.w) * ph + aA3;
    }
    float4 bb0 = *(const float4*)&b2[c0];
    float4 bb1 = *(const float4*)&b2[c0 + 4];
    float4 oA, oB;
    oA.x = ((float)aA0[0] + (float)aB0[0]) + bb0.x;
    oA.y = ((float)aA0[1] + (float)aB0[1]) + bb0.y;
    oA.z = ((float)aA1[0] + (float)aB1[0]) + bb0.z;
    oA.w = ((float)aA1[1] + (float)aB1[1]) + bb0.w;
    oB.x = ((float)aA2[0] + (float)aB2[0]) + bb1.x;
    oB.y = ((float)aA2[1] + (float)aB2[1]) + bb1.y;
    oB.z = ((float)aA3[0] + (float)aB3[0]) + bb1.z;
    oB.w = ((float)aA3[1] + (float)aB3[1]) + bb1.w;
    *(float4*)&out[(size_t)n * OUTC + c0] = oA;
    *(float4*)&out[(size_t)n * OUTC + c0 + 4] = oB;
}

// ---------------- launch ----------------
extern "C" void kernel_launch(void* const* d_in, const int* in_sizes, int n_in,
                              void* d_out, int out_size, void* d_ws, size_t ws_size,
                              hipStream_t stream) {
    const float* x   = (const float*)d_in[0];
    const int*   ei  = (const int*)  d_in[1];
    const float* W1  = (const float*)d_in[2];
    const float* b1  = (const float*)d_in[3];
    const float* as1 = (const float*)d_in[4];
    const float* ad1 = (const float*)d_in[5];
    const float* W2  = (const float*)d_in[6];
    const float* b2  = (const float*)d_in[7];
    const float* as2 = (const float*)d_in[8];
    const float* ad2 = (const float*)d_in[9];
    float* out = (float*)d_out;

    char* ws = (char*)d_ws;
    size_t off = 0;
    auto alloc = [&](size_t bytes) -> void* {
        void* p = ws + off;
        off = (off + bytes + 255) & ~(size_t)255;
        return p;
    };
    ushort* xh    = (ushort*)alloc((size_t)MPAD * INC * 2);
    ushort* w1t   = (ushort*)alloc((size_t)D1 * INC * 2);
    ushort* w2t   = (ushort*)alloc((size_t)OUTC * D1 * 2);
    ushort* h1h   = (ushort*)alloc((size_t)MPAD * D1 * 2);
    ushort* out1h = (ushort*)alloc((size_t)MPAD * D1 * 2);
    ushort* h2h   = (ushort*)alloc((size_t)MPAD * OUTC * 2);
    float*  es1   = (float*)alloc((size_t)NNODES * NH * 4);
    float*  ed1   = (float*)alloc((size_t)NNODES * NH * 4);
    float*  es2   = (float*)alloc((size_t)NNODES * 4);
    float*  ed2   = (float*)alloc((size_t)NNODES * 4);
    int*    deg   = (int*)alloc((size_t)NNODES * 4);
    int*    rs    = (int*)alloc((size_t)(NNODES + 1) * 4);
    int*    cur   = (int*)alloc((size_t)NNODES * 4);
    int*    csr   = (int*)alloc((size_t)ETOT * 4);

    // CSR build
    hipMemsetAsync(deg, 0, (size_t)NNODES * 4, stream);
    count_deg<<<(ETOT + 255) / 256, 256, 0, stream>>>(ei, deg);
    scan_deg<<<1, 1024, 0, stream>>>(deg, rs, cur);
    scatter_edges<<<(ETOT + 255) / 256, 256, 0, stream>>>(ei, cur, csr);

    // dtype prep + zero the dots2 accumulators (es2,ed2 are adjacent allocs)
    cast_f16<<<(NNODES * INC / 4 + 255) / 256, 256, 0, stream>>>(x, xh, NNODES * INC / 4);
    cast_wT<<<(INC * D1 + 255) / 256, 256, 0, stream>>>(W1, w1t, INC, D1);
    cast_wT<<<(D1 * OUTC + 255) / 256, 256, 0, stream>>>(W2, w2t, D1, OUTC);
    hipMemsetAsync(es2, 0, (size_t)((char*)csr - (char*)es2) > 0 ?
                   (size_t)((char*)deg - (char*)es2) : 0, stream);  // zero es2+ed2 region

    // layer 1 (GEMM + fused dots)
    gemm1_f16<INC><<<dim3(MPAD / 128, D1 / 128), 256, 0, stream>>>(
        xh, w1t, h1h, as1, ad1, es1, ed1, NNODES, D1);
    attn1<<<NNODES / 4, 256, 0, stream>>>(h1h, es1, ed1, rs, csr, b1, out1h);

    // layer 2 (GEMM + fused dots2 via atomics)
    gemm2_f16<D1><<<dim3(MPAD / 64, OUTC / 128), 256, 0, stream>>>(
        out1h, w2t, h2h, as2, ad2, es2, ed2, NNODES, OUTC);
    attn2<<<NNODES / 16, 256, 0, stream>>>(h2h, es2, ed2, rs, csr, b2, out);
}